// Round 6
// baseline (1361.723 us; speedup 1.0000x reference)
//
#include <hip/hip_runtime.h>
#include <math.h>

#define NT 64
#define KN 48
#define TOBS 30
#define NPRED 15
#define EMB 64
#define NODE 128
#define EDGE 256
#define ATTD 64
#define CNN 512
#define GNN 1024
#define GTT 512
#define KKA 320
#define TMAX 44

typedef _Float16 f16;
typedef f16 f16x8 __attribute__((ext_vector_type(8)));
typedef f16 f16x2 __attribute__((ext_vector_type(2)));
typedef float f32x4 __attribute__((ext_vector_type(4)));

__device__ __forceinline__ float rcp_f(float x) { return __builtin_amdgcn_rcpf(x); }
__device__ __forceinline__ float sigm(float x) {
  return rcp_f(1.f + __expf(-x));
}
__device__ __forceinline__ float tanh_f(float x) {
  float xx = fminf(fmaxf(x, -20.f), 20.f);
  float e = __expf(-2.f * xx);
  return (1.f - e) * rcp_f(1.f + e);
}
__device__ __forceinline__ void glds16(const f16* g, const f16* l) {
  __builtin_amdgcn_global_load_lds(
      (const __attribute__((address_space(1))) void*)g,
      (__attribute__((address_space(3))) void*)l, 16, 0, 0);
}

// ---------------- prep: swizzle weights to MFMA-fragment-major f16 ----------------
// Wn_sw flat idx = kk*32768 + p*16384 + w*2048 + g*512 + lane*8 + j
//   value = Wn_rowmajor[col][k], col = g*256 + p*128 + w*16 + (lane&15),
//                                k   = kk*32 + (lane>>4)*8 + j
// Wt_sw flat idx = (c8*512 + col)*8 + j ; value = Wt_rowmajor[col][c8*8+j]
__global__ __launch_bounds__(256) void prep_kernel(
    const float* __restrict__ Wih_n, const float* __restrict__ Whh_n,
    const float* __restrict__ bih_n, const float* __restrict__ bhh_n,
    const float* __restrict__ Wih_t, const float* __restrict__ Whh_t,
    const float* __restrict__ bih_t, const float* __restrict__ bhh_t,
    const int* __restrict__ t_hist, const int* __restrict__ n_hist,
    f16* __restrict__ Wn, f16* __restrict__ Wt,
    float* __restrict__ bias_n, float* __restrict__ bias_t,
    int* __restrict__ gt_arr, int* __restrict__ gn_arr, float* __restrict__ cn_arr)
{
  const int gid = blockIdx.x * 256 + threadIdx.x;
  const int nthr = gridDim.x * 256;

  for (int idx = gid; idx < GNN * KKA; idx += nthr) {
    const int j    = idx & 7;
    const int lane = (idx >> 3) & 63;
    const int g    = (idx >> 9) & 3;
    const int w    = (idx >> 11) & 7;
    const int p    = (idx >> 14) & 1;
    const int kk   = idx >> 15;
    const int col = g * 256 + p * 128 + w * 16 + (lane & 15);
    const int k   = kk * 32 + (lane >> 4) * 8 + j;
    const float v = (k < EMB) ? Wih_n[col * EMB + k] : Whh_n[col * EDGE + (k - EMB)];
    Wn[idx] = (f16)v;
  }
  for (int idx = gid; idx < GTT * 192; idx += nthr) {
    const int j = idx & 7;
    const int col = (idx >> 3) & 511;
    const int c8 = idx >> 12;
    const int k = c8 * 8 + j;
    const float v = (k < EMB) ? Wih_t[col * EMB + k] : Whh_t[col * NODE + (k - EMB)];
    Wt[idx] = (f16)v;
  }
  for (int idx = gid; idx < GNN; idx += nthr) bias_n[idx] = bih_n[idx] + bhh_n[idx];
  for (int idx = gid; idx < GTT; idx += nthr) bias_t[idx] = bih_t[idx] + bhh_t[idx];

  if (blockIdx.x == 0 && threadIdx.x < 352) {
    const int t = (threadIdx.x >> 3) + 1;   // 1..44
    const int part = threadIdx.x & 7;
    int any_t = 0, cnt = 0;
    if (t < TOBS) {
      const int thr = TOBS - t;
      for (int nn = part; nn < NT; nn += 8) any_t |= (t_hist[nn] > thr) ? 1 : 0;
      for (int m = part; m < NT * KN; m += 8) cnt += (n_hist[m] > thr) ? 1 : 0;
    } else { any_t = (part == 0); cnt = (part == 0) ? NT * KN : 0; }
    #pragma unroll
    for (int off = 1; off < 8; off <<= 1) {
      any_t |= __shfl_xor(any_t, off);
      cnt   += __shfl_xor(cnt, off);
    }
    if (part == 0) {
      gt_arr[t] = any_t;
      gn_arr[t] = (any_t && cnt > 0) ? 1 : 0;
      cn_arr[t] = (float)cnt;
    }
  }
}

// ---------------- main: one 512-thread workgroup per target ----------------
// P2: Wn streamed through LDS via async global_load_lds, 20 units of 32KB,
// double-buffered, one barrier per unit (m97 pattern). MFMA weights via ds_read_b128.
__global__ __launch_bounds__(512, 2) void model_kernel(
    const float* __restrict__ img, const float* __restrict__ tabs,
    const float* __restrict__ trel, const float* __restrict__ tstep,
    const float* __restrict__ nabs_g, const float* __restrict__ nstep_g,
    const int* __restrict__ thist_g, const int* __restrict__ nhist_g,
    const float* __restrict__ W_disp, const float* __restrict__ b_disp,
    const float* __restrict__ W_att_t, const float* __restrict__ b_att_t,
    const float* __restrict__ W_att_n, const float* __restrict__ b_att_n,
    const float* __restrict__ W_pred, const float* __restrict__ b_pred,
    const f16* __restrict__ Wn, const f16* __restrict__ Wt,
    const float* __restrict__ bias_n, const float* __restrict__ bias_t,
    const int* __restrict__ gt_arr, const int* __restrict__ gn_arr,
    const float* __restrict__ cn_arr,
    float* __restrict__ out)
{
  __shared__ f16 Wbuf[2][16384];     // 2 x 32KB weight stream chunks
  __shared__ f16 Ax[KN][EMB + 8];
  __shared__ f16 Ah[2][KN][EDGE + 8];
  __shared__ float s_tht[NODE], s_tct[NODE];
  __shared__ f16  s_th16[NODE];
  __shared__ f16  s_x16[EMB];
  __shared__ float s_Ht[EDGE];
  __shared__ float s_g[GTT];
  __shared__ float s_bt[GTT];
  __shared__ float s_at[ATTD];
  __shared__ float s_sc[KN], s_w[KN];
  __shared__ float s_scal[8];        // [0..1]=cabs [2..3]=crel [4..5]=cstep
  __shared__ float s_pimg[2];
  __shared__ int   s_nh[KN];
  __shared__ float s_wp[2][384];     // [0:128)=tht part, [128:384)=Ht part
  __shared__ float s_wan0[ATTD], s_wan1[ATTD], s_ban[ATTD];
  __shared__ float s_wat0[ATTD], s_wat1[ATTD], s_bat[ATTD];
  __shared__ float s_wd0[EMB], s_wd1[EMB], s_bd[EMB];

  const int tid  = threadIdx.x;
  const int n    = blockIdx.x;
  const int w    = tid >> 6;     // wave 0..7
  const int lane = tid & 63;
  const int cl   = lane & 15;
  const int kq   = lane >> 4;    // 0..3
  const int koff = kq * 8;

  // ---- one-time init / LDS caching ----
  for (int i = tid; i < 2 * KN * (EDGE + 8); i += 512) ((f16*)Ah)[i] = (f16)0.f;
  for (int i = tid; i < NODE; i += 512) { s_tht[i] = 0.f; s_tct[i] = 0.f; s_th16[i] = (f16)0.f; }
  for (int i = tid; i < EDGE; i += 512) s_Ht[i] = 0.f;
  for (int i = tid; i < GTT; i += 512) s_bt[i] = bias_t[i];
  for (int i = tid; i < 768; i += 512) {
    const int ww = i / 384, j = i - ww * 384;
    s_wp[ww][j] = (j < 128) ? W_pred[ww * 896 + j] : W_pred[ww * 896 + 640 + (j - 128)];
  }
  if (tid < KN) s_nh[tid] = nhist_g[n * KN + tid];
  if (tid < 8) s_scal[tid] = 0.f;
  if (tid >= 64 && tid < 128) {
    const int a = tid - 64;
    s_wan0[a] = W_att_n[a * 2]; s_wan1[a] = W_att_n[a * 2 + 1]; s_ban[a] = b_att_n[a];
  }
  if (tid >= 128 && tid < 192) {
    const int a = tid - 128;
    s_wat0[a] = W_att_t[a * 2]; s_wat1[a] = W_att_t[a * 2 + 1]; s_bat[a] = b_att_t[a];
  }
  if (tid >= 192 && tid < 256) {
    const int e = tid - 192;
    s_wd0[e] = W_disp[e * 2]; s_wd1[e] = W_disp[e * 2 + 1]; s_bd[e] = b_disp[e];
  }
  const int thist = thist_g[n];

  // img @ W_pred (constant part) + b_pred
  if (w < 2) {
    float s = 0.f;
    for (int j = lane; j < CNN; j += 64) s += img[n * CNN + j] * W_pred[w * 896 + 128 + j];
    for (int off = 32; off; off >>= 1) s += __shfl_down(s, off);
    if (lane == 0) s_pimg[w] = s + b_pred[w];
  }

  // persistent per-lane nearby cell state: pass p, rows rt*16+kq*4+jj, e = p*128+w*16+cl
  float creg[2][3][4];
  #pragma unroll
  for (int a = 0; a < 2; ++a)
    #pragma unroll
    for (int b = 0; b < 3; ++b)
      #pragma unroll
      for (int c = 0; c < 4; ++c) creg[a][b][c] = 0.f;

  float bias_q[2][4];
  #pragma unroll
  for (int p = 0; p < 2; ++p)
    #pragma unroll
    for (int g = 0; g < 4; ++g)
      bias_q[p][g] = bias_n[g * 256 + p * 128 + w * 16 + cl];

  // per-wave base pointers for the weight stream (f16 units)
  // unit (p,kk): global base = kk*32768 + p*16384; wave slice + w*2048 + g*512 + lane*8
  const f16* gW  = Wn + (size_t)w * 2048 + (size_t)lane * 8;
  f16* lW = &Wbuf[0][w * 2048 + lane * 8];   // + buf*16384 + g*512
  int prv = 0;

  __syncthreads();

  for (int t = 1; t <= TMAX; ++t) {
    const bool is_obs = (t < TOBS);
    const int tc = is_obs ? t : (TOBS - 1);
    const int gate_t = gt_arr[t];
    const int gate_n = gn_arr[t];
    const float currN = cn_arr[t];

    // ---- P0: pred_out + scalar state update ----
    if (!is_obs) {
      if (w < 2) {
        float s = 0.f;
        for (int j = lane; j < NODE; j += 64) s += s_tht[j] * s_wp[w][j];
        for (int j = lane; j < EDGE; j += 64) s += s_Ht[j] * s_wp[w][128 + j];
        for (int off = 32; off; off >>= 1) s += __shfl_down(s, off);
        if (lane == 0) {
          const float p = s + s_pimg[w];
          const float cabs = s_scal[w] + p;
          const float crel = s_scal[2 + w] + p;
          s_scal[w] = cabs; s_scal[2 + w] = crel; s_scal[4 + w] = p;
          out[(n * NPRED + (t - TOBS)) * 2 + w] = crel;
        }
      }
    } else if (tid < 2) {
      const int d = tid;
      s_scal[d]     = tabs[(n * TOBS + tc) * 2 + d];
      s_scal[2 + d] = trel[(n * TOBS + tc) * 2 + d];
      s_scal[4 + d] = tstep[(n * TOBS + tc) * 2 + d];
    }
    __syncthreads();  // A

    // ---- P1: stage Ax (frozen after t=30), s_x16, s_at; prefetch unit 0 ----
    if (t <= TOBS) {
      for (int i = tid; i < KN * EMB; i += 512) {
        const int k = i >> 6, e = i & 63;
        const float s0 = nstep_g[((n * KN + k) * TOBS + tc) * 2 + 0];
        const float s1 = nstep_g[((n * KN + k) * TOBS + tc) * 2 + 1];
        Ax[k][e] = (f16)(s0 * s_wd0[e] + s1 * s_wd1[e] + s_bd[e]);
      }
    }
    if (tid >= 448) {
      const int e = tid - 448;
      s_x16[e] = (f16)(s_scal[4] * s_wd0[e] + s_scal[5] * s_wd1[e] + s_bd[e]);
    }
    if (tid >= 384 && tid < 448) {
      const int a = tid - 384;
      s_at[a] = s_scal[2] * s_wat0[a] + s_scal[3] * s_wat1[a] + s_bat[a];
    }
    if (gate_n) {
      #pragma unroll
      for (int g = 0; g < 4; ++g)
        glds16(gW + g * 512, lW + g * 512);   // unit 0 -> buf 0
    }
    __syncthreads();  // B (drains unit-0 prefetch)

    // ---- P2: nearby LSTM via MFMA; LDS-streamed weights; two e-half passes ----
    const int nxt = prv ^ 1;
    if (gate_n) {
      f32x4 acc[3][4];
      #pragma unroll
      for (int rt = 0; rt < 3; ++rt)
        #pragma unroll
        for (int g = 0; g < 4; ++g) acc[rt][g] = (f32x4){0.f, 0.f, 0.f, 0.f};

      #pragma unroll
      for (int u = 0; u < 20; ++u) {
        const int p  = (u < 10) ? 0 : 1;
        const int kk = u - p * 10;
        // prefetch unit u+1 into buf[(u+1)&1]
        if (u < 19) {
          const int p1  = (u + 1 < 10) ? 0 : 1;
          const int kk1 = (u + 1) - p1 * 10;
          const f16* gs = gW + (size_t)kk1 * 32768 + p1 * 16384;
          f16* ls = lW + ((u + 1) & 1) * 16384;
          #pragma unroll
          for (int g = 0; g < 4; ++g)
            glds16(gs + g * 512, ls + g * 512);
        }
        // weights for unit u from LDS
        f16x8 bf[4];
        #pragma unroll
        for (int g = 0; g < 4; ++g)
          bf[g] = *(const f16x8*)(lW + (u & 1) * 16384 + g * 512);
        f16x8 af[3];
        #pragma unroll
        for (int rt = 0; rt < 3; ++rt) {
          const int row = rt * 16 + cl;
          const f16* ap = (kk < 2) ? &Ax[row][kk * 32 + koff]
                                   : &Ah[prv][row][(kk - 2) * 32 + koff];
          af[rt] = *(const f16x8*)ap;
        }
        #pragma unroll
        for (int g = 0; g < 4; ++g)
          #pragma unroll
          for (int rt = 0; rt < 3; ++rt)
            acc[rt][g] = __builtin_amdgcn_mfma_f32_16x16x32_f16(af[rt], bf[g], acc[rt][g], 0, 0, 0);

        // end of pass: activation, write h half into Ah[nxt], reset acc
        if (u == 9 || u == 19) {
          const int e_p = p * 128 + w * 16 + cl;
          #pragma unroll
          for (int rt = 0; rt < 3; ++rt) {
            #pragma unroll
            for (int jj = 0; jj < 4; ++jj) {
              const int row = rt * 16 + kq * 4 + jj;
              const bool nm = is_obs ? (s_nh[row] > (TOBS - t)) : true;
              if (nm) {
                const float iv = acc[rt][0][jj] + bias_q[p][0];
                const float fv = acc[rt][1][jj] + bias_q[p][1];
                const float gv = acc[rt][2][jj] + bias_q[p][2];
                const float ov = acc[rt][3][jj] + bias_q[p][3];
                const float c2 = sigm(fv) * creg[p][rt][jj] + sigm(iv) * tanh_f(gv);
                creg[p][rt][jj] = c2;
                Ah[nxt][row][e_p] = (f16)(sigm(ov) * tanh_f(c2));
              } else {
                Ah[nxt][row][e_p] = Ah[prv][row][e_p];
              }
            }
          }
          if (u == 9) {
            #pragma unroll
            for (int rt = 0; rt < 3; ++rt)
              #pragma unroll
              for (int g = 0; g < 4; ++g) acc[rt][g] = (f32x4){0.f, 0.f, 0.f, 0.f};
          }
        }
        __syncthreads();  // per-unit barrier (drains prefetch, releases buf)
      }
      prv = nxt;
    }

    // ---- P4: target gate dots via v_dot2 (all 512) + attention scores (tid<48) ----
    const bool tmask = is_obs ? (thist > (TOBS - t)) : true;
    const bool do_t = gate_t && tmask;
    if (do_t) {
      float g = s_bt[tid];
      const f16x2* xt2 = (const f16x2*)s_x16;    // 32 pairs
      const f16x2* th2 = (const f16x2*)s_th16;   // 64 pairs
      const f16x8* wp = (const f16x8*)(Wt + tid * 8);
      #pragma unroll
      for (int c8 = 0; c8 < 8; ++c8) {
        const f16x8 wv = wp[c8 * 512];
        #pragma unroll
        for (int j2 = 0; j2 < 4; ++j2) {
          f16x2 wpair = {wv[2 * j2], wv[2 * j2 + 1]};
          g = __builtin_amdgcn_fdot2(wpair, xt2[c8 * 4 + j2], g, false);
        }
      }
      #pragma unroll
      for (int c8 = 8; c8 < 24; ++c8) {
        const f16x8 wv = wp[c8 * 512];
        #pragma unroll
        for (int j2 = 0; j2 < 4; ++j2) {
          f16x2 wpair = {wv[2 * j2], wv[2 * j2 + 1]};
          g = __builtin_amdgcn_fdot2(wpair, th2[(c8 - 8) * 4 + j2], g, false);
        }
      }
      s_g[tid] = g;
    }
    if (gate_n && tid < KN) {
      const int k = tid;
      const float a0 = nabs_g[((n * KN + k) * TOBS + tc) * 2 + 0] - s_scal[0];
      const float a1 = nabs_g[((n * KN + k) * TOBS + tc) * 2 + 1] - s_scal[1];
      const bool nm = is_obs ? (s_nh[k] > (TOBS - t)) : true;
      float sc = 0.f;
      for (int a = 0; a < ATTD; ++a)
        sc += (a0 * s_wan0[a] + a1 * s_wan1[a] + s_ban[a]) * s_at[a];
      sc *= currN * 0.125f;
      s_sc[k] = nm ? sc : 0.f;
      s_w[k]  = nm ? 1.f : 0.f;
    }
    __syncthreads();  // E

    // ---- P5: target cell update (tid<128) + softmax (wave 4) ----
    if (do_t && tid < NODE) {
      const float iv = s_g[tid], fv = s_g[NODE + tid];
      const float gv = s_g[2 * NODE + tid], ov = s_g[3 * NODE + tid];
      const float c2 = sigm(fv) * s_tct[tid] + sigm(iv) * tanh_f(gv);
      s_tct[tid] = c2;
      const float nh = sigm(ov) * tanh_f(c2);
      s_tht[tid] = nh;
      s_th16[tid] = (f16)nh;
    }
    if (gate_n && w == 4) {
      const bool act = lane < KN;
      const float sc = act ? s_sc[lane] : -1.0e30f;
      const float mf = act ? s_w[lane] : 0.f;
      float mx = sc;
      #pragma unroll
      for (int off = 32; off; off >>= 1) mx = fmaxf(mx, __shfl_xor(mx, off));
      float num = __expf(sc - mx) * mf;
      float sum = num;
      #pragma unroll
      for (int off = 32; off; off >>= 1) sum += __shfl_xor(sum, off);
      if (act) s_w[lane] = num * rcp_f(sum + 1e-6f);
    }
    __syncthreads();  // F

    // ---- P6: Ht (reads updated Ah[prv]) ----
    if (gate_n && tid < EDGE) {
      float h = 0.f;
      for (int k = 0; k < KN; ++k) h += (float)Ah[prv][k][tid] * s_w[k];
      s_Ht[tid] = h;
    }
    __syncthreads();  // G
  }
}

extern "C" void kernel_launch(void* const* d_in, const int* in_sizes, int n_in,
                              void* d_out, int out_size, void* d_ws, size_t ws_size,
                              hipStream_t stream) {
  const float* img    = (const float*)d_in[0];
  const float* tabs   = (const float*)d_in[1];
  const float* trel   = (const float*)d_in[2];
  const float* tstep  = (const float*)d_in[3];
  const float* nabs   = (const float*)d_in[4];
  const float* nstep  = (const float*)d_in[6];
  const int*   thist  = (const int*)d_in[7];
  const int*   nhist  = (const int*)d_in[8];
  const float* W_disp = (const float*)d_in[9];
  const float* b_disp = (const float*)d_in[10];
  const float* Wih_t  = (const float*)d_in[11];
  const float* Whh_t  = (const float*)d_in[12];
  const float* bih_t  = (const float*)d_in[13];
  const float* bhh_t  = (const float*)d_in[14];
  const float* Wih_n  = (const float*)d_in[15];
  const float* Whh_n  = (const float*)d_in[16];
  const float* bih_n  = (const float*)d_in[17];
  const float* bhh_n  = (const float*)d_in[18];
  const float* W_att_t = (const float*)d_in[19];
  const float* b_att_t = (const float*)d_in[20];
  const float* W_att_n = (const float*)d_in[21];
  const float* b_att_n = (const float*)d_in[22];
  const float* W_pred  = (const float*)d_in[23];
  const float* b_pred  = (const float*)d_in[24];

  char* ws = (char*)d_ws;
  f16*   Wn     = (f16*)(ws);             // 655360 B
  f16*   Wt     = (f16*)(ws + 655360);    // 196608 B
  float* bias_n = (float*)(ws + 851968);  // 4096 B
  float* bias_t = (float*)(ws + 856064);  // 2048 B
  int*   gt_arr = (int*)(ws + 858112);
  int*   gn_arr = (int*)(ws + 858304);
  float* cn_arr = (float*)(ws + 858496);

  prep_kernel<<<64, 256, 0, stream>>>(Wih_n, Whh_n, bih_n, bhh_n, Wih_t, Whh_t,
                                      bih_t, bhh_t, thist, nhist, Wn, Wt,
                                      bias_n, bias_t, gt_arr, gn_arr, cn_arr);
  model_kernel<<<NT, 512, 0, stream>>>(img, tabs, trel, tstep, nabs, nstep,
                                       thist, nhist, W_disp, b_disp,
                                       W_att_t, b_att_t, W_att_n, b_att_n,
                                       W_pred, b_pred,
                                       Wn, Wt, bias_n, bias_t,
                                       gt_arr, gn_arr, cn_arr,
                                       (float*)d_out);
}

// Round 7
// 957.205 us; speedup vs baseline: 1.4226x; 1.4226x over previous
//
#include <hip/hip_runtime.h>
#include <math.h>

#define NT 64
#define KN 48
#define TOBS 30
#define NPRED 15
#define EMB 64
#define NODE 128
#define EDGE 256
#define ATTD 64
#define CNN 512
#define GNN 1024
#define GTT 512
#define KKA 320
#define TMAX 44

typedef _Float16 f16;
typedef f16 f16x8 __attribute__((ext_vector_type(8)));
typedef f16 f16x2 __attribute__((ext_vector_type(2)));
typedef float f32x4 __attribute__((ext_vector_type(4)));

__device__ __forceinline__ float rcp_f(float x) { return __builtin_amdgcn_rcpf(x); }
__device__ __forceinline__ float sigm(float x) { return rcp_f(1.f + __expf(-x)); }
__device__ __forceinline__ float tanh_f(float x) {
  float xx = fminf(fmaxf(x, -20.f), 20.f);
  float e = __expf(-2.f * xx);
  return (1.f - e) * rcp_f(1.f + e);
}
// agent-scope coherent load (L2-bypass; does not invalidate caches)
__device__ __forceinline__ unsigned ldcoh(const unsigned* p) {
  return __hip_atomic_load(p, __ATOMIC_RELAXED, __HIP_MEMORY_SCOPE_AGENT);
}
__device__ __forceinline__ float ldcohf(const float* p) {
  unsigned u = __hip_atomic_load((const unsigned*)p, __ATOMIC_RELAXED, __HIP_MEMORY_SCOPE_AGENT);
  return __builtin_bit_cast(float, u);
}

// ---------------- prep: swizzle weights, combine biases, gates, zero counters ----------------
// Wn_sw flat idx = ((((h*8+w)*10 + kk)*4 + g)*64 + lane)*8 + j
//   value = Wn_rm[col][k], col = g*256 + h*128 + w*16 + (lane&15), k = kk*32 + (lane>>4)*8 + j
// Wt_sw flat idx = (c8*512 + col)*8 + j ; value = Wt_rm[col][c8*8+j]
__global__ __launch_bounds__(256) void prep_kernel(
    const float* __restrict__ Wih_n, const float* __restrict__ Whh_n,
    const float* __restrict__ bih_n, const float* __restrict__ bhh_n,
    const float* __restrict__ Wih_t, const float* __restrict__ Whh_t,
    const float* __restrict__ bih_t, const float* __restrict__ bhh_t,
    const int* __restrict__ t_hist, const int* __restrict__ n_hist,
    f16* __restrict__ Wn, f16* __restrict__ Wt,
    float* __restrict__ bias_n, float* __restrict__ bias_t,
    int* __restrict__ gt_arr, int* __restrict__ gn_arr, float* __restrict__ cn_arr,
    unsigned* __restrict__ ctr)
{
  const int gid = blockIdx.x * 256 + threadIdx.x;
  const int nthr = gridDim.x * 256;

  if (gid < NT) ctr[gid] = 0u;

  for (int idx = gid; idx < GNN * KKA; idx += nthr) {
    const int j    = idx & 7;
    const int lane = (idx >> 3) & 63;
    const int g    = (idx >> 9) & 3;
    const int r    = idx >> 11;        // (h*8+w)*10 + kk
    const int kk   = r % 10;
    const int s    = r / 10;           // h*8 + w
    const int w    = s & 7;
    const int h    = s >> 3;
    const int col = g * 256 + h * 128 + w * 16 + (lane & 15);
    const int k   = kk * 32 + (lane >> 4) * 8 + j;
    const float v = (k < EMB) ? Wih_n[col * EMB + k] : Whh_n[col * EDGE + (k - EMB)];
    Wn[idx] = (f16)v;
  }
  for (int idx = gid; idx < GTT * 192; idx += nthr) {
    const int j = idx & 7;
    const int col = (idx >> 3) & 511;
    const int c8 = idx >> 12;
    const int k = c8 * 8 + j;
    const float v = (k < EMB) ? Wih_t[col * EMB + k] : Whh_t[col * NODE + (k - EMB)];
    Wt[idx] = (f16)v;
  }
  for (int idx = gid; idx < GNN; idx += nthr) bias_n[idx] = bih_n[idx] + bhh_n[idx];
  for (int idx = gid; idx < GTT; idx += nthr) bias_t[idx] = bih_t[idx] + bhh_t[idx];

  if (blockIdx.x == 0 && threadIdx.x < 352) {
    const int t = (threadIdx.x >> 3) + 1;   // 1..44
    const int part = threadIdx.x & 7;
    int any_t = 0, cnt = 0;
    if (t < TOBS) {
      const int thr = TOBS - t;
      for (int nn = part; nn < NT; nn += 8) any_t |= (t_hist[nn] > thr) ? 1 : 0;
      for (int m = part; m < NT * KN; m += 8) cnt += (n_hist[m] > thr) ? 1 : 0;
    } else { any_t = (part == 0); cnt = (part == 0) ? NT * KN : 0; }
    #pragma unroll
    for (int off = 1; off < 8; off <<= 1) {
      any_t |= __shfl_xor(any_t, off);
      cnt   += __shfl_xor(cnt, off);
    }
    if (part == 0) {
      gt_arr[t] = any_t;
      gn_arr[t] = (any_t && cnt > 0) ? 1 : 0;
      cn_arr[t] = (float)cnt;
    }
  }
}

// ---------------- main: TWO 512-thread blocks per target (e-dim halves) ----------------
// block = 2n + h. Block h computes nearby-gate cols {g*256 + h*128 + [0,128)} and target
// cols [h*256,(h+1)*256). Exchange: h-slice (48x128 f16) + gate slice (256 f32) via global,
// one per-target device-scope barrier per step. Scalar chain replicated in both blocks.
__global__ __launch_bounds__(512, 2) void model_kernel(
    const float* __restrict__ img, const float* __restrict__ tabs,
    const float* __restrict__ trel, const float* __restrict__ tstep,
    const float* __restrict__ nabs_g, const float* __restrict__ nstep_g,
    const int* __restrict__ thist_g, const int* __restrict__ nhist_g,
    const float* __restrict__ W_disp, const float* __restrict__ b_disp,
    const float* __restrict__ W_att_t, const float* __restrict__ b_att_t,
    const float* __restrict__ W_att_n, const float* __restrict__ b_att_n,
    const float* __restrict__ W_pred, const float* __restrict__ b_pred,
    const f16* __restrict__ Wn, const f16* __restrict__ Wt,
    const float* __restrict__ bias_n, const float* __restrict__ bias_t,
    const int* __restrict__ gt_arr, const int* __restrict__ gn_arr,
    const float* __restrict__ cn_arr,
    unsigned* __restrict__ ctr, unsigned short* __restrict__ Hglob,
    float* __restrict__ Gglob,
    float* __restrict__ out)
{
  __shared__ f16 Ax[KN][72];
  __shared__ f16 Ah[KN][264];
  __shared__ float s_tht[NODE], s_tct[NODE];
  __shared__ f16  s_th16[NODE];
  __shared__ float s_Ht[EDGE];
  __shared__ f16  s_x16[EMB];
  __shared__ float s_at[ATTD];
  __shared__ float s_sc[KN], s_w[KN];
  __shared__ float s_scal[8];        // [0..1]=cabs [2..3]=crel [4..5]=cstep
  __shared__ float s_pimg[2];
  __shared__ int   s_nh[KN];
  __shared__ float s_wp[2][384];     // [0:128)=tht part, [128:384)=Ht part
  __shared__ float s_wan0[ATTD], s_wan1[ATTD], s_ban[ATTD];
  __shared__ float s_wat0[ATTD], s_wat1[ATTD], s_bat[ATTD];
  __shared__ float s_wd0[EMB], s_wd1[EMB], s_bd[EMB];

  const int tid  = threadIdx.x;
  const int n    = blockIdx.x >> 1;
  const int hb   = blockIdx.x & 1;   // e-half
  const int w    = tid >> 6;         // wave 0..7
  const int lane = tid & 63;
  const int cl   = lane & 15;
  const int kq   = lane >> 4;
  const int koff = kq * 8;

  // ---- one-time init / LDS caching ----
  for (int i = tid; i < KN * 264; i += 512) ((f16*)Ah)[i] = (f16)0.f;
  for (int i = tid; i < NODE; i += 512) { s_tht[i] = 0.f; s_tct[i] = 0.f; s_th16[i] = (f16)0.f; }
  for (int i = tid; i < EDGE; i += 512) s_Ht[i] = 0.f;
  for (int i = tid; i < 768; i += 512) {
    const int ww = i / 384, j = i - ww * 384;
    s_wp[ww][j] = (j < 128) ? W_pred[ww * 896 + j] : W_pred[ww * 896 + 640 + (j - 128)];
  }
  if (tid < KN) s_nh[tid] = nhist_g[n * KN + tid];
  if (tid < 8) s_scal[tid] = 0.f;
  if (tid >= 64 && tid < 128) {
    const int a = tid - 64;
    s_wan0[a] = W_att_n[a * 2]; s_wan1[a] = W_att_n[a * 2 + 1]; s_ban[a] = b_att_n[a];
  }
  if (tid >= 128 && tid < 192) {
    const int a = tid - 128;
    s_wat0[a] = W_att_t[a * 2]; s_wat1[a] = W_att_t[a * 2 + 1]; s_bat[a] = b_att_t[a];
  }
  if (tid >= 192 && tid < 256) {
    const int e = tid - 192;
    s_wd0[e] = W_disp[e * 2]; s_wd1[e] = W_disp[e * 2 + 1]; s_bd[e] = b_disp[e];
  }
  const int thist = thist_g[n];

  if (w < 2) {
    float s = 0.f;
    for (int j = lane; j < CNN; j += 64) s += img[n * CNN + j] * W_pred[w * 896 + 128 + j];
    for (int off = 32; off; off >>= 1) s += __shfl_down(s, off);
    if (lane == 0) s_pimg[w] = s + b_pred[w];
  }

  // per-lane nearby cell state: rows rt*16+kq*4+jj, e = hb*128 + w*16 + cl
  float creg[3][4];
  #pragma unroll
  for (int b = 0; b < 3; ++b)
    #pragma unroll
    for (int c = 0; c < 4; ++c) creg[b][c] = 0.f;

  float bias_q[4];
  #pragma unroll
  for (int g = 0; g < 4; ++g) bias_q[g] = bias_n[g * 256 + hb * 128 + w * 16 + cl];

  const f16* gW = Wn + ((size_t)(hb * 8 + w) * 10) * 2048 + (size_t)lane * 8;  // + kk*2048 + g*512
  const int e_g = hb * 128 + w * 16 + cl;
  unsigned* myctr = ctr + n;
  int bn = 0;

  __syncthreads();

  for (int t = 1; t <= TMAX; ++t) {
    const bool is_obs = (t < TOBS);
    const int tc = is_obs ? t : (TOBS - 1);
    const int gate_t = gt_arr[t];
    const int gate_n = gn_arr[t];
    const float currN = cn_arr[t];
    const bool tmask = is_obs ? (thist > (TOBS - t)) : true;
    const bool do_t = gate_t && tmask;
    const bool need_x = (gate_n || do_t);
    const int par = bn & 1;

    // ---- P0: pred_out + scalar state update (replicated) ----
    if (!is_obs) {
      if (w < 2) {
        float s = 0.f;
        for (int j = lane; j < NODE; j += 64) s += s_tht[j] * s_wp[w][j];
        for (int j = lane; j < EDGE; j += 64) s += s_Ht[j] * s_wp[w][128 + j];
        for (int off = 32; off; off >>= 1) s += __shfl_down(s, off);
        if (lane == 0) {
          const float p = s + s_pimg[w];
          const float cabs = s_scal[w] + p;
          const float crel = s_scal[2 + w] + p;
          s_scal[w] = cabs; s_scal[2 + w] = crel; s_scal[4 + w] = p;
          if (hb == 0) out[(n * NPRED + (t - TOBS)) * 2 + w] = crel;
        }
      }
    } else if (tid < 2) {
      const int d = tid;
      s_scal[d]     = tabs[(n * TOBS + tc) * 2 + d];
      s_scal[2 + d] = trel[(n * TOBS + tc) * 2 + d];
      s_scal[4 + d] = tstep[(n * TOBS + tc) * 2 + d];
    }
    __syncthreads();  // A

    // ---- P1: stage Ax (frozen after t=30), x16, at ----
    if (t <= TOBS) {
      for (int i = tid; i < KN * EMB; i += 512) {
        const int k = i >> 6, e = i & 63;
        const float s0 = nstep_g[((n * KN + k) * TOBS + tc) * 2 + 0];
        const float s1 = nstep_g[((n * KN + k) * TOBS + tc) * 2 + 1];
        Ax[k][e] = (f16)(s0 * s_wd0[e] + s1 * s_wd1[e] + s_bd[e]);
      }
    }
    if (tid >= 448) {
      const int e = tid - 448;
      s_x16[e] = (f16)(s_scal[4] * s_wd0[e] + s_scal[5] * s_wd1[e] + s_bd[e]);
    }
    if (tid >= 384 && tid < 448) {
      const int a = tid - 384;
      s_at[a] = s_scal[2] * s_wat0[a] + s_scal[3] * s_wat1[a] + s_bat[a];
    }
    __syncthreads();  // B

    // ---- P2: nearby LSTM (own 128 e-dims, all 4 gates) via MFMA ----
    if (gate_n) {
      f32x4 acc[3][4];
      #pragma unroll
      for (int rt = 0; rt < 3; ++rt)
        #pragma unroll
        for (int g = 0; g < 4; ++g) acc[rt][g] = (f32x4){0.f, 0.f, 0.f, 0.f};

      #pragma unroll
      for (int kk = 0; kk < 10; ++kk) {
        f16x8 bf[4];
        #pragma unroll
        for (int g = 0; g < 4; ++g)
          bf[g] = *(const f16x8*)(gW + kk * 2048 + g * 512);
        f16x8 af[3];
        #pragma unroll
        for (int rt = 0; rt < 3; ++rt) {
          const int row = rt * 16 + cl;
          const f16* ap = (kk < 2) ? &Ax[row][kk * 32 + koff]
                                   : &Ah[row][(kk - 2) * 32 + koff];
          af[rt] = *(const f16x8*)ap;
        }
        #pragma unroll
        for (int g = 0; g < 4; ++g)
          #pragma unroll
          for (int rt = 0; rt < 3; ++rt)
            acc[rt][g] = __builtin_amdgcn_mfma_f32_16x16x32_f16(af[rt], bf[g], acc[rt][g], 0, 0, 0);
      }

      // activation; write h-slice to Hglob[par]
      unsigned short* Hg = Hglob + ((size_t)(par * NT + n) * KN) * 256;
      #pragma unroll
      for (int rt = 0; rt < 3; ++rt) {
        #pragma unroll
        for (int jj = 0; jj < 4; ++jj) {
          const int row = rt * 16 + kq * 4 + jj;
          const bool nm = is_obs ? (s_nh[row] > (TOBS - t)) : true;
          f16 hv;
          if (nm) {
            const float iv = acc[rt][0][jj] + bias_q[0];
            const float fv = acc[rt][1][jj] + bias_q[1];
            const float gv = acc[rt][2][jj] + bias_q[2];
            const float ov = acc[rt][3][jj] + bias_q[3];
            const float c2 = sigm(fv) * creg[rt][jj] + sigm(iv) * tanh_f(gv);
            creg[rt][jj] = c2;
            hv = (f16)(sigm(ov) * tanh_f(c2));
          } else {
            hv = Ah[row][e_g];
          }
          Hg[row * 256 + e_g] = __builtin_bit_cast(unsigned short, hv);
        }
      }
    }

    // ---- P3: target gate slice (own 256 cols) -> Gglob[par] ----
    if (do_t && tid < 256) {
      const int col = hb * 256 + tid;
      float g = bias_t[col];
      const f16x2* xt2 = (const f16x2*)s_x16;
      const f16x2* th2 = (const f16x2*)s_th16;
      const f16x8* wp = (const f16x8*)(Wt + col * 8);
      #pragma unroll
      for (int c8 = 0; c8 < 8; ++c8) {
        const f16x8 wv = wp[c8 * 512];
        #pragma unroll
        for (int j2 = 0; j2 < 4; ++j2) {
          f16x2 wpair = {wv[2 * j2], wv[2 * j2 + 1]};
          g = __builtin_amdgcn_fdot2(wpair, xt2[c8 * 4 + j2], g, false);
        }
      }
      #pragma unroll
      for (int c8 = 8; c8 < 24; ++c8) {
        const f16x8 wv = wp[c8 * 512];
        #pragma unroll
        for (int j2 = 0; j2 < 4; ++j2) {
          f16x2 wpair = {wv[2 * j2], wv[2 * j2 + 1]};
          g = __builtin_amdgcn_fdot2(wpair, th2[(c8 - 8) * 4 + j2], g, false);
        }
      }
      Gglob[(size_t)(par * NT + n) * GTT + col] = g;
    }

    // ---- scores (replicated) ----
    if (gate_n && tid >= 256 && tid < 256 + KN) {
      const int k = tid - 256;
      const float a0 = nabs_g[((n * KN + k) * TOBS + tc) * 2 + 0] - s_scal[0];
      const float a1 = nabs_g[((n * KN + k) * TOBS + tc) * 2 + 1] - s_scal[1];
      const bool nm = is_obs ? (s_nh[k] > (TOBS - t)) : true;
      float sc = 0.f;
      for (int a = 0; a < ATTD; ++a)
        sc += (a0 * s_wan0[a] + a1 * s_wan1[a] + s_ban[a]) * s_at[a];
      sc *= currN * 0.125f;
      s_sc[k] = nm ? sc : 0.f;
      s_w[k]  = nm ? 1.f : 0.f;
    }
    __syncthreads();  // C (scores + all global stores issued)

    // softmax (wave 4) runs while tid0 does the cross-block barrier
    if (gate_n && w == 4) {
      const bool act = lane < KN;
      const float sc = act ? s_sc[lane] : -1.0e30f;
      const float mf = act ? s_w[lane] : 0.f;
      float mx = sc;
      #pragma unroll
      for (int off = 32; off; off >>= 1) mx = fmaxf(mx, __shfl_xor(mx, off));
      float num = __expf(sc - mx) * mf;
      float sum = num;
      #pragma unroll
      for (int off = 32; off; off >>= 1) sum += __shfl_xor(sum, off);
      if (act) s_w[lane] = num * rcp_f(sum + 1e-6f);
    }
    if (need_x && tid == 0) {
      // release: flushes this XCD's L2 (our Hglob/Gglob stores) then bump counter
      __hip_atomic_fetch_add(myctr, 1u, __ATOMIC_RELEASE, __HIP_MEMORY_SCOPE_AGENT);
      const unsigned expect = 2u * (unsigned)(bn + 1);
      while (__hip_atomic_load(myctr, __ATOMIC_RELAXED, __HIP_MEMORY_SCOPE_AGENT) < expect)
        __builtin_amdgcn_s_sleep(8);
    }
    __syncthreads();  // D (past barrier; softmax done)

    // ---- phase B: pull exchanged state (agent-coherent loads, no cache nuke) ----
    if (gate_n) {
      const unsigned* Hg32 = (const unsigned*)(Hglob + ((size_t)(par * NT + n) * KN) * 256);
      for (int i = tid; i < KN * 128; i += 512) {
        const unsigned v = ldcoh(Hg32 + i);
        const int row = i >> 7, c2 = i & 127;
        *(unsigned*)&Ah[row][c2 * 2] = v;
      }
    }
    if (do_t && tid < NODE) {
      const float* Gg = Gglob + (size_t)(par * NT + n) * GTT;
      const float iv = ldcohf(Gg + tid);
      const float fv = ldcohf(Gg + NODE + tid);
      const float gv = ldcohf(Gg + 2 * NODE + tid);
      const float ov = ldcohf(Gg + 3 * NODE + tid);
      const float c2 = sigm(fv) * s_tct[tid] + sigm(iv) * tanh_f(gv);
      s_tct[tid] = c2;
      const float nh = sigm(ov) * tanh_f(c2);
      s_tht[tid] = nh;
      s_th16[tid] = (f16)nh;
    }
    __syncthreads();  // E (Ah + target state ready)

    // ---- Ht (replicated) ----
    if (gate_n && tid < EDGE) {
      float h = 0.f;
      for (int k = 0; k < KN; ++k) h += (float)Ah[k][tid] * s_w[k];
      s_Ht[tid] = h;
    }
    if (need_x) bn++;
    __syncthreads();  // F (Ht ready for next P0)
  }
}

extern "C" void kernel_launch(void* const* d_in, const int* in_sizes, int n_in,
                              void* d_out, int out_size, void* d_ws, size_t ws_size,
                              hipStream_t stream) {
  const float* img    = (const float*)d_in[0];
  const float* tabs   = (const float*)d_in[1];
  const float* trel   = (const float*)d_in[2];
  const float* tstep  = (const float*)d_in[3];
  const float* nabs   = (const float*)d_in[4];
  const float* nstep  = (const float*)d_in[6];
  const int*   thist  = (const int*)d_in[7];
  const int*   nhist  = (const int*)d_in[8];
  const float* W_disp = (const float*)d_in[9];
  const float* b_disp = (const float*)d_in[10];
  const float* Wih_t  = (const float*)d_in[11];
  const float* Whh_t  = (const float*)d_in[12];
  const float* bih_t  = (const float*)d_in[13];
  const float* bhh_t  = (const float*)d_in[14];
  const float* Wih_n  = (const float*)d_in[15];
  const float* Whh_n  = (const float*)d_in[16];
  const float* bih_n  = (const float*)d_in[17];
  const float* bhh_n  = (const float*)d_in[18];
  const float* W_att_t = (const float*)d_in[19];
  const float* b_att_t = (const float*)d_in[20];
  const float* W_att_n = (const float*)d_in[21];
  const float* b_att_n = (const float*)d_in[22];
  const float* W_pred  = (const float*)d_in[23];
  const float* b_pred  = (const float*)d_in[24];

  char* ws = (char*)d_ws;
  f16*      Wn     = (f16*)(ws);              // 655360 B
  f16*      Wt     = (f16*)(ws + 655360);     // 196608 B
  float*    bias_n = (float*)(ws + 851968);   // 4096 B
  float*    bias_t = (float*)(ws + 856064);   // 2048 B
  int*      gt_arr = (int*)(ws + 858112);
  int*      gn_arr = (int*)(ws + 858304);
  float*    cn_arr = (float*)(ws + 858496);
  unsigned* ctr    = (unsigned*)(ws + 860160);            // 256 B
  unsigned short* Hglob = (unsigned short*)(ws + 1048576); // 2*64*48*256*2 = 3145728 B
  float*    Gglob  = (float*)(ws + 4194304);               // 2*64*512*4 = 262144 B

  prep_kernel<<<64, 256, 0, stream>>>(Wih_n, Whh_n, bih_n, bhh_n, Wih_t, Whh_t,
                                      bih_t, bhh_t, thist, nhist, Wn, Wt,
                                      bias_n, bias_t, gt_arr, gn_arr, cn_arr, ctr);
  model_kernel<<<2 * NT, 512, 0, stream>>>(img, tabs, trel, tstep, nabs, nstep,
                                           thist, nhist, W_disp, b_disp,
                                           W_att_t, b_att_t, W_att_n, b_att_n,
                                           W_pred, b_pred,
                                           Wn, Wt, bias_n, bias_t,
                                           gt_arr, gn_arr, cn_arr,
                                           ctr, Hglob, Gglob,
                                           (float*)d_out);
}

// Round 8
// 798.333 us; speedup vs baseline: 1.7057x; 1.1990x over previous
//
#include <hip/hip_runtime.h>
#include <math.h>

#define NT 64
#define KN 48
#define TOBS 30
#define NPRED 15
#define EMB 64
#define NODE 128
#define EDGE 256
#define ATTD 64
#define CNN 512
#define GNN 1024
#define GTT 512
#define KKA 320
#define TMAX 44

typedef _Float16 f16;
typedef f16 f16x8 __attribute__((ext_vector_type(8)));
typedef f16 f16x2 __attribute__((ext_vector_type(2)));
typedef float f32x4 __attribute__((ext_vector_type(4)));

__device__ __forceinline__ float rcp_f(float x) { return __builtin_amdgcn_rcpf(x); }
__device__ __forceinline__ float sigm(float x) { return rcp_f(1.f + __expf(-x)); }
__device__ __forceinline__ float tanh_f(float x) {
  float xx = fminf(fmaxf(x, -20.f), 20.f);
  float e = __expf(-2.f * xx);
  return (1.f - e) * rcp_f(1.f + e);
}
// agent-scope coherent (MALL) load/store — bypass per-XCD L2, no wbl2 needed
__device__ __forceinline__ unsigned ldcoh(const unsigned* p) {
  return __hip_atomic_load(p, __ATOMIC_RELAXED, __HIP_MEMORY_SCOPE_AGENT);
}
__device__ __forceinline__ float ldcohf(const float* p) {
  unsigned u = __hip_atomic_load((const unsigned*)p, __ATOMIC_RELAXED, __HIP_MEMORY_SCOPE_AGENT);
  return __builtin_bit_cast(float, u);
}
__device__ __forceinline__ void stcoh(unsigned* p, unsigned v) {
  __hip_atomic_store(p, v, __ATOMIC_RELAXED, __HIP_MEMORY_SCOPE_AGENT);
}
__device__ __forceinline__ void stcohf(float* p, float v) {
  __hip_atomic_store((unsigned*)p, __builtin_bit_cast(unsigned, v),
                     __ATOMIC_RELAXED, __HIP_MEMORY_SCOPE_AGENT);
}

// ---------------- prep: swizzle weights, combine biases, gates, zero flags ----------------
// Wn_sw flat idx = ((((h*8+w)*10 + kk)*4 + g)*64 + lane)*8 + j
//   value = Wn_rm[col][k], col = g*256 + h*128 + w*16 + (lane&15), k = kk*32 + (lane>>4)*8 + j
// Wt_sw flat idx = (c8*512 + col)*8 + j ; value = Wt_rm[col][c8*8+j]
__global__ __launch_bounds__(256) void prep_kernel(
    const float* __restrict__ Wih_n, const float* __restrict__ Whh_n,
    const float* __restrict__ bih_n, const float* __restrict__ bhh_n,
    const float* __restrict__ Wih_t, const float* __restrict__ Whh_t,
    const float* __restrict__ bih_t, const float* __restrict__ bhh_t,
    const int* __restrict__ t_hist, const int* __restrict__ n_hist,
    f16* __restrict__ Wn, f16* __restrict__ Wt,
    float* __restrict__ bias_n, float* __restrict__ bias_t,
    int* __restrict__ gt_arr, int* __restrict__ gn_arr, float* __restrict__ cn_arr,
    unsigned* __restrict__ flags)
{
  const int gid = blockIdx.x * 256 + threadIdx.x;
  const int nthr = gridDim.x * 256;

  if (gid < 2 * NT) flags[gid] = 0u;

  for (int idx = gid; idx < GNN * KKA; idx += nthr) {
    const int j    = idx & 7;
    const int lane = (idx >> 3) & 63;
    const int g    = (idx >> 9) & 3;
    const int r    = idx >> 11;        // (h*8+w)*10 + kk
    const int kk   = r % 10;
    const int s    = r / 10;           // h*8 + w
    const int w    = s & 7;
    const int h    = s >> 3;
    const int col = g * 256 + h * 128 + w * 16 + (lane & 15);
    const int k   = kk * 32 + (lane >> 4) * 8 + j;
    const float v = (k < EMB) ? Wih_n[col * EMB + k] : Whh_n[col * EDGE + (k - EMB)];
    Wn[idx] = (f16)v;
  }
  for (int idx = gid; idx < GTT * 192; idx += nthr) {
    const int j = idx & 7;
    const int col = (idx >> 3) & 511;
    const int c8 = idx >> 12;
    const int k = c8 * 8 + j;
    const float v = (k < EMB) ? Wih_t[col * EMB + k] : Whh_t[col * NODE + (k - EMB)];
    Wt[idx] = (f16)v;
  }
  for (int idx = gid; idx < GNN; idx += nthr) bias_n[idx] = bih_n[idx] + bhh_n[idx];
  for (int idx = gid; idx < GTT; idx += nthr) bias_t[idx] = bih_t[idx] + bhh_t[idx];

  if (blockIdx.x == 0 && threadIdx.x < 352) {
    const int t = (threadIdx.x >> 3) + 1;   // 1..44
    const int part = threadIdx.x & 7;
    int any_t = 0, cnt = 0;
    if (t < TOBS) {
      const int thr = TOBS - t;
      for (int nn = part; nn < NT; nn += 8) any_t |= (t_hist[nn] > thr) ? 1 : 0;
      for (int m = part; m < NT * KN; m += 8) cnt += (n_hist[m] > thr) ? 1 : 0;
    } else { any_t = (part == 0); cnt = (part == 0) ? NT * KN : 0; }
    #pragma unroll
    for (int off = 1; off < 8; off <<= 1) {
      any_t |= __shfl_xor(any_t, off);
      cnt   += __shfl_xor(cnt, off);
    }
    if (part == 0) {
      gt_arr[t] = any_t;
      gn_arr[t] = (any_t && cnt > 0) ? 1 : 0;
      cn_arr[t] = (float)cnt;
    }
  }
}

// ---------------- main: TWO 512-thread blocks per target ----------------
// block b: n = b&63, hb = b>>6 (blocks n and n+64 pair -> same XCD under round-robin).
// Block hb computes nearby-gate e-dims [hb*128,(hb+1)*128) (all 4 gates) and target
// node-dims [hb*64,(hb+1)*64) (all 4 gates). Exchange: 12KB h-slice + 64-float h_t via
// MALL-coherent atomics; flag store/poll sync (no RMW, no wbl2).
__global__ __launch_bounds__(512, 2) void model_kernel(
    const float* __restrict__ img, const float* __restrict__ tabs,
    const float* __restrict__ trel, const float* __restrict__ tstep,
    const float* __restrict__ nabs_g, const float* __restrict__ nstep_g,
    const int* __restrict__ thist_g, const int* __restrict__ nhist_g,
    const float* __restrict__ W_disp, const float* __restrict__ b_disp,
    const float* __restrict__ W_att_t, const float* __restrict__ b_att_t,
    const float* __restrict__ W_att_n, const float* __restrict__ b_att_n,
    const float* __restrict__ W_pred, const float* __restrict__ b_pred,
    const f16* __restrict__ Wn, const f16* __restrict__ Wt,
    const float* __restrict__ bias_n, const float* __restrict__ bias_t,
    const int* __restrict__ gt_arr, const int* __restrict__ gn_arr,
    const float* __restrict__ cn_arr,
    unsigned* __restrict__ flags, unsigned* __restrict__ Hglob,
    float* __restrict__ Tglob,
    float* __restrict__ out)
{
  __shared__ f16 Ax[KN][72];
  __shared__ f16 Ah[KN][264];
  __shared__ float s_tht[NODE];
  __shared__ float s_tct[64];        // own node-dim half only
  __shared__ f16  s_th16[NODE];
  __shared__ float s_Ht[EDGE];
  __shared__ f16  s_x16[EMB];
  __shared__ float s_g[256];
  __shared__ float s_bt[256];
  __shared__ float s_at[ATTD];
  __shared__ float s_sc[KN], s_w[KN];
  __shared__ float s_scal[8];        // [0..1]=cabs [2..3]=crel [4..5]=cstep
  __shared__ float s_pimg[2];
  __shared__ int   s_nh[KN];
  __shared__ float s_wp[2][384];
  __shared__ float s_wan0[ATTD], s_wan1[ATTD], s_ban[ATTD];
  __shared__ float s_wat0[ATTD], s_wat1[ATTD], s_bat[ATTD];
  __shared__ float s_wd0[EMB], s_wd1[EMB], s_bd[EMB];

  const int tid  = threadIdx.x;
  const int n    = blockIdx.x & 63;
  const int hb   = blockIdx.x >> 6;
  const int w    = tid >> 6;
  const int lane = tid & 63;
  const int cl   = lane & 15;
  const int kq   = lane >> 4;
  const int koff = kq * 8;

  // ---- one-time init / LDS caching ----
  for (int i = tid; i < KN * 264; i += 512) ((f16*)Ah)[i] = (f16)0.f;
  for (int i = tid; i < NODE; i += 512) { s_tht[i] = 0.f; s_th16[i] = (f16)0.f; }
  if (tid < 64) s_tct[tid] = 0.f;
  for (int i = tid; i < EDGE; i += 512) s_Ht[i] = 0.f;
  if (tid < 256) {
    const int g = tid >> 6, dl = tid & 63;
    s_bt[tid] = bias_t[g * 128 + hb * 64 + dl];
  }
  for (int i = tid; i < 768; i += 512) {
    const int ww = i / 384, j = i - ww * 384;
    s_wp[ww][j] = (j < 128) ? W_pred[ww * 896 + j] : W_pred[ww * 896 + 640 + (j - 128)];
  }
  if (tid < KN) s_nh[tid] = nhist_g[n * KN + tid];
  if (tid < 8) s_scal[tid] = 0.f;
  if (tid >= 64 && tid < 128) {
    const int a = tid - 64;
    s_wan0[a] = W_att_n[a * 2]; s_wan1[a] = W_att_n[a * 2 + 1]; s_ban[a] = b_att_n[a];
  }
  if (tid >= 128 && tid < 192) {
    const int a = tid - 128;
    s_wat0[a] = W_att_t[a * 2]; s_wat1[a] = W_att_t[a * 2 + 1]; s_bat[a] = b_att_t[a];
  }
  if (tid >= 192 && tid < 256) {
    const int e = tid - 192;
    s_wd0[e] = W_disp[e * 2]; s_wd1[e] = W_disp[e * 2 + 1]; s_bd[e] = b_disp[e];
  }
  const int thist = thist_g[n];

  if (w < 2) {
    float s = 0.f;
    for (int j = lane; j < CNN; j += 64) s += img[n * CNN + j] * W_pred[w * 896 + 128 + j];
    for (int off = 32; off; off >>= 1) s += __shfl_down(s, off);
    if (lane == 0) s_pimg[w] = s + b_pred[w];
  }

  // per-lane nearby cell state: rows rt*16+kq*4+jj, e = hb*128 + w*16 + cl
  float creg[3][4];
  #pragma unroll
  for (int b = 0; b < 3; ++b)
    #pragma unroll
    for (int c = 0; c < 4; ++c) creg[b][c] = 0.f;

  float bias_q[4];
  #pragma unroll
  for (int g = 0; g < 4; ++g) bias_q[g] = bias_n[g * 256 + hb * 128 + w * 16 + cl];

  const f16* gW = Wn + ((size_t)(hb * 8 + w) * 10) * 2048 + (size_t)lane * 8;
  const int e_g = hb * 128 + w * 16 + cl;
  unsigned* myflag = flags + n * 2 + hb;
  unsigned* otflag = flags + n * 2 + (1 - hb);
  int bn = 0;

  __syncthreads();

  for (int t = 1; t <= TMAX; ++t) {
    const bool is_obs = (t < TOBS);
    const int tc = is_obs ? t : (TOBS - 1);
    const int gate_t = gt_arr[t];
    const int gate_n = gn_arr[t];
    const float currN = cn_arr[t];
    const bool tmask = is_obs ? (thist > (TOBS - t)) : true;
    const bool do_t = gate_t && tmask;
    const bool need_x = (gate_n || do_t);
    const int par = bn & 1;

    // ---- P0: pred_out + scalar state update (replicated) ----
    if (!is_obs) {
      if (w < 2) {
        float s = 0.f;
        for (int j = lane; j < NODE; j += 64) s += s_tht[j] * s_wp[w][j];
        for (int j = lane; j < EDGE; j += 64) s += s_Ht[j] * s_wp[w][128 + j];
        for (int off = 32; off; off >>= 1) s += __shfl_down(s, off);
        if (lane == 0) {
          const float p = s + s_pimg[w];
          const float cabs = s_scal[w] + p;
          const float crel = s_scal[2 + w] + p;
          s_scal[w] = cabs; s_scal[2 + w] = crel; s_scal[4 + w] = p;
          if (hb == 0) out[(n * NPRED + (t - TOBS)) * 2 + w] = crel;
        }
      }
    } else if (tid < 2) {
      const int d = tid;
      s_scal[d]     = tabs[(n * TOBS + tc) * 2 + d];
      s_scal[2 + d] = trel[(n * TOBS + tc) * 2 + d];
      s_scal[4 + d] = tstep[(n * TOBS + tc) * 2 + d];
    }
    __syncthreads();  // A

    // ---- P1: stage Ax (frozen after t=30), x16, at ----
    if (t <= TOBS) {
      for (int i = tid; i < KN * EMB; i += 512) {
        const int k = i >> 6, e = i & 63;
        const float s0 = nstep_g[((n * KN + k) * TOBS + tc) * 2 + 0];
        const float s1 = nstep_g[((n * KN + k) * TOBS + tc) * 2 + 1];
        Ax[k][e] = (f16)(s0 * s_wd0[e] + s1 * s_wd1[e] + s_bd[e]);
      }
    }
    if (tid >= 448) {
      const int e = tid - 448;
      s_x16[e] = (f16)(s_scal[4] * s_wd0[e] + s_scal[5] * s_wd1[e] + s_bd[e]);
    }
    if (tid >= 384 && tid < 448) {
      const int a = tid - 384;
      s_at[a] = s_scal[2] * s_wat0[a] + s_scal[3] * s_wat1[a] + s_bat[a];
    }
    __syncthreads();  // B

    // ---- P2: nearby LSTM (own 128 e-dims) via MFMA; h kept in regs + MALL store ----
    f16 hreg[3][4];
    if (gate_n) {
      f32x4 acc[3][4];
      #pragma unroll
      for (int rt = 0; rt < 3; ++rt)
        #pragma unroll
        for (int g = 0; g < 4; ++g) acc[rt][g] = (f32x4){0.f, 0.f, 0.f, 0.f};

      #pragma unroll
      for (int kk = 0; kk < 10; ++kk) {
        f16x8 bf[4];
        #pragma unroll
        for (int g = 0; g < 4; ++g)
          bf[g] = *(const f16x8*)(gW + kk * 2048 + g * 512);
        f16x8 af[3];
        #pragma unroll
        for (int rt = 0; rt < 3; ++rt) {
          const int row = rt * 16 + cl;
          const f16* ap = (kk < 2) ? &Ax[row][kk * 32 + koff]
                                   : &Ah[row][(kk - 2) * 32 + koff];
          af[rt] = *(const f16x8*)ap;
        }
        #pragma unroll
        for (int g = 0; g < 4; ++g)
          #pragma unroll
          for (int rt = 0; rt < 3; ++rt)
            acc[rt][g] = __builtin_amdgcn_mfma_f32_16x16x32_f16(af[rt], bf[g], acc[rt][g], 0, 0, 0);
      }

      unsigned* Hg = Hglob + (size_t)(par * NT + n) * (KN * 128);
      #pragma unroll
      for (int rt = 0; rt < 3; ++rt) {
        #pragma unroll
        for (int jj = 0; jj < 4; ++jj) {
          const int row = rt * 16 + kq * 4 + jj;
          const bool nm = is_obs ? (s_nh[row] > (TOBS - t)) : true;
          f16 hv;
          if (nm) {
            const float iv = acc[rt][0][jj] + bias_q[0];
            const float fv = acc[rt][1][jj] + bias_q[1];
            const float gv = acc[rt][2][jj] + bias_q[2];
            const float ov = acc[rt][3][jj] + bias_q[3];
            const float c2 = sigm(fv) * creg[rt][jj] + sigm(iv) * tanh_f(gv);
            creg[rt][jj] = c2;
            hv = (f16)(sigm(ov) * tanh_f(c2));
          } else {
            hv = Ah[row][e_g];
          }
          hreg[rt][jj] = hv;
          // pack (e, e+1) pairs via shfl; even-cl lanes store dwords to MALL
          const unsigned lo = (unsigned)__builtin_bit_cast(unsigned short, hv);
          const unsigned hi = (unsigned)__shfl_down((int)lo, 1);
          if (!(cl & 1))
            stcoh(Hg + row * 128 + (e_g >> 1), lo | (hi << 16));
        }
      }
    }

    // ---- P3: target gate dots (own 256 cols = all gates x own 64 node dims) ----
    if (do_t && tid < 256) {
      const int g = tid >> 6, dl = tid & 63;
      const int col = g * 128 + hb * 64 + dl;
      float gg = s_bt[tid];
      const f16x2* xt2 = (const f16x2*)s_x16;
      const f16x2* th2 = (const f16x2*)s_th16;
      const f16x8* wp = (const f16x8*)(Wt + col * 8);
      #pragma unroll
      for (int c8 = 0; c8 < 8; ++c8) {
        const f16x8 wv = wp[c8 * 512];
        #pragma unroll
        for (int j2 = 0; j2 < 4; ++j2) {
          f16x2 wpair = {wv[2 * j2], wv[2 * j2 + 1]};
          gg = __builtin_amdgcn_fdot2(wpair, xt2[c8 * 4 + j2], gg, false);
        }
      }
      #pragma unroll
      for (int c8 = 8; c8 < 24; ++c8) {
        const f16x8 wv = wp[c8 * 512];
        #pragma unroll
        for (int j2 = 0; j2 < 4; ++j2) {
          f16x2 wpair = {wv[2 * j2], wv[2 * j2 + 1]};
          gg = __builtin_amdgcn_fdot2(wpair, th2[(c8 - 8) * 4 + j2], gg, false);
        }
      }
      s_g[tid] = gg;
    }
    // ---- attention scores (replicated) ----
    if (gate_n && tid >= 256 && tid < 256 + KN) {
      const int k = tid - 256;
      const float a0 = nabs_g[((n * KN + k) * TOBS + tc) * 2 + 0] - s_scal[0];
      const float a1 = nabs_g[((n * KN + k) * TOBS + tc) * 2 + 1] - s_scal[1];
      const bool nm = is_obs ? (s_nh[k] > (TOBS - t)) : true;
      float sc = 0.f;
      for (int a = 0; a < ATTD; ++a)
        sc += (a0 * s_wan0[a] + a1 * s_wan1[a] + s_ban[a]) * s_at[a];
      sc *= currN * 0.125f;
      s_sc[k] = nm ? sc : 0.f;
      s_w[k]  = nm ? 1.f : 0.f;
    }
    __syncthreads();  // C1 (s_g ready)

    // ---- cell update (own 64 node dims) + softmax, then publish ----
    if (do_t && tid < 64) {
      const int d = hb * 64 + tid;
      const float iv = s_g[tid], fv = s_g[64 + tid];
      const float gv = s_g[128 + tid], ov = s_g[192 + tid];
      const float c2 = sigm(fv) * s_tct[tid] + sigm(iv) * tanh_f(gv);
      s_tct[tid] = c2;
      const float nh = sigm(ov) * tanh_f(c2);
      s_tht[d] = nh;
      s_th16[d] = (f16)nh;
      stcohf(Tglob + ((size_t)(par * NT + n) * 2 + hb) * 64 + tid, nh);
    }
    if (gate_n && w == 4) {
      const bool act = lane < KN;
      const float sc = act ? s_sc[lane] : -1.0e30f;
      const float mf = act ? s_w[lane] : 0.f;
      float mx = sc;
      #pragma unroll
      for (int off = 32; off; off >>= 1) mx = fmaxf(mx, __shfl_xor(mx, off));
      float num = __expf(sc - mx) * mf;
      float sum = num;
      #pragma unroll
      for (int off = 32; off; off >>= 1) sum += __shfl_xor(sum, off);
      if (act) s_w[lane] = num * rcp_f(sum + 1e-6f);
    }
    __syncthreads();  // C2 (drains ALL waves' H/T MALL stores: vmcnt(0) before s_barrier)

    if (need_x && tid == 0) {
      const unsigned step = (unsigned)(bn + 1);
      stcoh(myflag, step);                       // publish: data already at MALL
      while (ldcoh(otflag) < step)
        __builtin_amdgcn_s_sleep(2);
    }
    __syncthreads();  // D

    // ---- pull: partner h-half + own regs -> Ah; partner h_t half ----
    if (gate_n) {
      const unsigned* Hg = Hglob + (size_t)(par * NT + n) * (KN * 128);
      const int ob = (1 - hb) * 64;
      for (int i = tid; i < KN * 64; i += 512) {
        const int row = i >> 6, c = i & 63;
        const unsigned v = ldcoh(Hg + row * 128 + ob + c);
        *(unsigned*)&Ah[row][(ob + c) * 2] = v;
      }
      #pragma unroll
      for (int rt = 0; rt < 3; ++rt)
        #pragma unroll
        for (int jj = 0; jj < 4; ++jj)
          Ah[rt * 16 + kq * 4 + jj][e_g] = hreg[rt][jj];
    }
    if (do_t && tid >= 448) {
      const int dl = tid - 448;
      const int d = (1 - hb) * 64 + dl;
      const float nh = ldcohf(Tglob + ((size_t)(par * NT + n) * 2 + (1 - hb)) * 64 + dl);
      s_tht[d] = nh;
      s_th16[d] = (f16)nh;
    }
    __syncthreads();  // E

    // ---- Ht (replicated) ----
    if (gate_n && tid < EDGE) {
      float h = 0.f;
      for (int k = 0; k < KN; ++k) h += (float)Ah[k][tid] * s_w[k];
      s_Ht[tid] = h;
    }
    if (need_x) bn++;
    __syncthreads();  // F
  }
}

extern "C" void kernel_launch(void* const* d_in, const int* in_sizes, int n_in,
                              void* d_out, int out_size, void* d_ws, size_t ws_size,
                              hipStream_t stream) {
  const float* img    = (const float*)d_in[0];
  const float* tabs   = (const float*)d_in[1];
  const float* trel   = (const float*)d_in[2];
  const float* tstep  = (const float*)d_in[3];
  const float* nabs   = (const float*)d_in[4];
  const float* nstep  = (const float*)d_in[6];
  const int*   thist  = (const int*)d_in[7];
  const int*   nhist  = (const int*)d_in[8];
  const float* W_disp = (const float*)d_in[9];
  const float* b_disp = (const float*)d_in[10];
  const float* Wih_t  = (const float*)d_in[11];
  const float* Whh_t  = (const float*)d_in[12];
  const float* bih_t  = (const float*)d_in[13];
  const float* bhh_t  = (const float*)d_in[14];
  const float* Wih_n  = (const float*)d_in[15];
  const float* Whh_n  = (const float*)d_in[16];
  const float* bih_n  = (const float*)d_in[17];
  const float* bhh_n  = (const float*)d_in[18];
  const float* W_att_t = (const float*)d_in[19];
  const float* b_att_t = (const float*)d_in[20];
  const float* W_att_n = (const float*)d_in[21];
  const float* b_att_n = (const float*)d_in[22];
  const float* W_pred  = (const float*)d_in[23];
  const float* b_pred  = (const float*)d_in[24];

  char* ws = (char*)d_ws;
  f16*      Wn     = (f16*)(ws);              // 655360 B
  f16*      Wt     = (f16*)(ws + 655360);     // 196608 B
  float*    bias_n = (float*)(ws + 851968);   // 4096 B
  float*    bias_t = (float*)(ws + 856064);   // 2048 B
  int*      gt_arr = (int*)(ws + 858112);
  int*      gn_arr = (int*)(ws + 858304);
  float*    cn_arr = (float*)(ws + 858496);
  unsigned* flags  = (unsigned*)(ws + 860160);             // 512 B
  unsigned* Hglob  = (unsigned*)(ws + 1048576);            // 2*64*48*128*4 = 3145728 B
  float*    Tglob  = (float*)(ws + 4194304);               // 2*64*2*64*4 = 131072 B

  prep_kernel<<<64, 256, 0, stream>>>(Wih_n, Whh_n, bih_n, bhh_n, Wih_t, Whh_t,
                                      bih_t, bhh_t, thist, nhist, Wn, Wt,
                                      bias_n, bias_t, gt_arr, gn_arr, cn_arr, flags);
  model_kernel<<<2 * NT, 512, 0, stream>>>(img, tabs, trel, tstep, nabs, nstep,
                                           thist, nhist, W_disp, b_disp,
                                           W_att_t, b_att_t, W_att_n, b_att_n,
                                           W_pred, b_pred,
                                           Wn, Wt, bias_n, bias_t,
                                           gt_arr, gn_arr, cn_arr,
                                           flags, Hglob, Tglob,
                                           (float*)d_out);
}

// Round 9
// 716.927 us; speedup vs baseline: 1.8994x; 1.1135x over previous
//
#include <hip/hip_runtime.h>
#include <math.h>

#define NT 64
#define KN 48
#define TOBS 30
#define NPRED 15
#define EMB 64
#define NODE 128
#define EDGE 256
#define ATTD 64
#define CNN 512
#define GNN 1024
#define GTT 512
#define KKA 320
#define TMAX 44

typedef _Float16 f16;
typedef f16 f16x8 __attribute__((ext_vector_type(8)));
typedef f16 f16x2 __attribute__((ext_vector_type(2)));
typedef float f32x4 __attribute__((ext_vector_type(4)));

__device__ __forceinline__ float rcp_f(float x) { return __builtin_amdgcn_rcpf(x); }
__device__ __forceinline__ float sigm(float x) { return rcp_f(1.f + __expf(-x)); }
__device__ __forceinline__ float tanh_f(float x) {
  float xx = fminf(fmaxf(x, -20.f), 20.f);
  float e = __expf(-2.f * xx);
  return (1.f - e) * rcp_f(1.f + e);
}
__device__ __forceinline__ unsigned ldcoh(const unsigned* p) {
  return __hip_atomic_load(p, __ATOMIC_RELAXED, __HIP_MEMORY_SCOPE_AGENT);
}
__device__ __forceinline__ float ldcohf(const float* p) {
  unsigned u = __hip_atomic_load((const unsigned*)p, __ATOMIC_RELAXED, __HIP_MEMORY_SCOPE_AGENT);
  return __builtin_bit_cast(float, u);
}
__device__ __forceinline__ void stcoh(unsigned* p, unsigned v) {
  __hip_atomic_store(p, v, __ATOMIC_RELAXED, __HIP_MEMORY_SCOPE_AGENT);
}
__device__ __forceinline__ void stcohf(float* p, float v) {
  __hip_atomic_store((unsigned*)p, __builtin_bit_cast(unsigned, v),
                     __ATOMIC_RELAXED, __HIP_MEMORY_SCOPE_AGENT);
}

// ---------------- prep (512 threads: fixes t=33..44 gate bug) ----------------
// Wn_sw flat idx = ((((h*8+w)*10 + kk)*4 + g)*64 + lane)*8 + j
//   value = Wn_rm[col][k], col = g*256 + h*128 + w*16 + (lane&15), k = kk*32 + (lane>>4)*8 + j
// Wt_sw flat idx = (c8*512 + col)*8 + j ; value = Wt_rm[col][c8*8+j]
__global__ __launch_bounds__(512) void prep_kernel(
    const float* __restrict__ Wih_n, const float* __restrict__ Whh_n,
    const float* __restrict__ bih_n, const float* __restrict__ bhh_n,
    const float* __restrict__ Wih_t, const float* __restrict__ Whh_t,
    const float* __restrict__ bih_t, const float* __restrict__ bhh_t,
    const int* __restrict__ t_hist, const int* __restrict__ n_hist,
    f16* __restrict__ Wn, f16* __restrict__ Wt,
    float* __restrict__ bias_n, float* __restrict__ bias_t,
    int* __restrict__ gt_arr, int* __restrict__ gn_arr, float* __restrict__ cn_arr,
    int* __restrict__ last29p, unsigned* __restrict__ flags)
{
  const int gid = blockIdx.x * 512 + threadIdx.x;
  const int nthr = gridDim.x * 512;
  __shared__ int sgn[TMAX + 1];

  if (gid < 2 * NT) flags[gid] = 0u;

  for (int idx = gid; idx < GNN * KKA; idx += nthr) {
    const int j    = idx & 7;
    const int lane = (idx >> 3) & 63;
    const int g    = (idx >> 9) & 3;
    const int r    = idx >> 11;
    const int kk   = r % 10;
    const int s    = r / 10;
    const int w    = s & 7;
    const int h    = s >> 3;
    const int col = g * 256 + h * 128 + w * 16 + (lane & 15);
    const int k   = kk * 32 + (lane >> 4) * 8 + j;
    const float v = (k < EMB) ? Wih_n[col * EMB + k] : Whh_n[col * EDGE + (k - EMB)];
    Wn[idx] = (f16)v;
  }
  for (int idx = gid; idx < GTT * 192; idx += nthr) {
    const int j = idx & 7;
    const int col = (idx >> 3) & 511;
    const int c8 = idx >> 12;
    const int k = c8 * 8 + j;
    const float v = (k < EMB) ? Wih_t[col * EMB + k] : Whh_t[col * NODE + (k - EMB)];
    Wt[idx] = (f16)v;
  }
  for (int idx = gid; idx < GNN; idx += nthr) bias_n[idx] = bih_n[idx] + bhh_n[idx];
  for (int idx = gid; idx < GTT; idx += nthr) bias_t[idx] = bih_t[idx] + bhh_t[idx];

  if (blockIdx.x == 0 && threadIdx.x < 352) {
    const int t = (threadIdx.x >> 3) + 1;   // 1..44
    const int part = threadIdx.x & 7;
    int any_t = 0, cnt = 0;
    if (t < TOBS) {
      const int thr = TOBS - t;
      for (int nn = part; nn < NT; nn += 8) any_t |= (t_hist[nn] > thr) ? 1 : 0;
      for (int m = part; m < NT * KN; m += 8) cnt += (n_hist[m] > thr) ? 1 : 0;
    } else { any_t = (part == 0); cnt = (part == 0) ? NT * KN : 0; }
    #pragma unroll
    for (int off = 1; off < 8; off <<= 1) {
      any_t |= __shfl_xor(any_t, off);
      cnt   += __shfl_xor(cnt, off);
    }
    if (part == 0) {
      const int gn = (any_t && cnt > 0) ? 1 : 0;
      gt_arr[t] = any_t;
      gn_arr[t] = gn;
      cn_arr[t] = (float)cnt;
      sgn[t] = gn;
    }
  }
  __syncthreads();
  if (blockIdx.x == 0 && threadIdx.x == 0) {
    int l = 30;   // if no gate_n step <=29, attention first matters at t=30
    for (int t = 29; t >= 1; --t) if (sgn[t]) { l = t; break; }
    last29p[0] = l;
  }
}

// ---------------- main: TWO 512-thread blocks per target (e-halves) ----------------
// kk 0..2 of each block's Wn slice LDS-resident; kk 3..9 streamed from L2.
// Attention (scores/softmax/Ht) only for t >= last29 (exact dead-code elim).
// Next-step staging moved between flag-publish and poll (off the serial path).
__global__ __launch_bounds__(512, 2) void model_kernel(
    const float* __restrict__ img, const float* __restrict__ tabs,
    const float* __restrict__ trel, const float* __restrict__ tstep,
    const float* __restrict__ nabs_g, const float* __restrict__ nstep_g,
    const int* __restrict__ thist_g, const int* __restrict__ nhist_g,
    const float* __restrict__ W_disp, const float* __restrict__ b_disp,
    const float* __restrict__ W_att_t, const float* __restrict__ b_att_t,
    const float* __restrict__ W_att_n, const float* __restrict__ b_att_n,
    const float* __restrict__ W_pred, const float* __restrict__ b_pred,
    const f16* __restrict__ Wn, const f16* __restrict__ Wt,
    const float* __restrict__ bias_n, const float* __restrict__ bias_t,
    const int* __restrict__ gt_arr, const int* __restrict__ gn_arr,
    const float* __restrict__ cn_arr, const int* __restrict__ last29p,
    unsigned* __restrict__ flags, unsigned* __restrict__ Hglob,
    float* __restrict__ Tglob,
    float* __restrict__ out)
{
  __shared__ f16 s_wlds[3 * 16384];   // kk 0..2: [kk][w][g][lane][8] = 96KB
  __shared__ f16 Ax[KN][72];
  __shared__ f16 Ah[KN][264];
  __shared__ float s_tht[NODE];
  __shared__ float s_tct[64];
  __shared__ f16  s_th16[NODE];
  __shared__ float s_Ht[EDGE];
  __shared__ f16  s_x16[EMB];
  __shared__ float s_g[256];
  __shared__ float s_bt[256];
  __shared__ float s_at[ATTD];
  __shared__ float s_sc[KN], s_w[KN];
  __shared__ float s_scal[8];
  __shared__ float s_pimg[2];
  __shared__ int   s_nh[KN];
  __shared__ float s_wp[2][384];
  __shared__ float s_wan0[ATTD], s_wan1[ATTD], s_ban[ATTD];
  __shared__ float s_wat0[ATTD], s_wat1[ATTD], s_bat[ATTD];
  __shared__ float s_wd0[EMB], s_wd1[EMB], s_bd[EMB];

  const int tid  = threadIdx.x;
  const int n    = blockIdx.x & 63;
  const int hb   = blockIdx.x >> 6;
  const int w    = tid >> 6;
  const int lane = tid & 63;
  const int cl   = lane & 15;
  const int kq   = lane >> 4;
  const int koff = kq * 8;

  // ---- one-time init ----
  for (int i = tid; i < KN * 264; i += 512) ((f16*)Ah)[i] = (f16)0.f;
  for (int i = tid; i < NODE; i += 512) { s_tht[i] = 0.f; s_th16[i] = (f16)0.f; }
  if (tid < 64) s_tct[tid] = 0.f;
  for (int i = tid; i < EDGE; i += 512) s_Ht[i] = 0.f;
  if (tid < 256) {
    const int g = tid >> 6, dl = tid & 63;
    s_bt[tid] = bias_t[g * 128 + hb * 64 + dl];
  }
  for (int i = tid; i < 768; i += 512) {
    const int ww = i / 384, j = i - ww * 384;
    s_wp[ww][j] = (j < 128) ? W_pred[ww * 896 + j] : W_pred[ww * 896 + 640 + (j - 128)];
  }
  if (tid < KN) s_nh[tid] = nhist_g[n * KN + tid];
  if (tid < 8) s_scal[tid] = 0.f;
  if (tid >= 64 && tid < 128) {
    const int a = tid - 64;
    s_wan0[a] = W_att_n[a * 2]; s_wan1[a] = W_att_n[a * 2 + 1]; s_ban[a] = b_att_n[a];
  }
  if (tid >= 128 && tid < 192) {
    const int a = tid - 128;
    s_wat0[a] = W_att_t[a * 2]; s_wat1[a] = W_att_t[a * 2 + 1]; s_bat[a] = b_att_t[a];
  }
  if (tid >= 192 && tid < 256) {
    const int e = tid - 192;
    s_wd0[e] = W_disp[e * 2]; s_wd1[e] = W_disp[e * 2 + 1]; s_bd[e] = b_disp[e];
  }
  const int thist = thist_g[n];
  const int last29 = last29p[0];

  // LDS-resident weight units kk=0..2 (block's own slice)
  for (int i = tid; i < 3 * 8 * 256; i += 512) {
    const int c  = i & 255;
    const int wv = (i >> 8) & 7;
    const int kk = i >> 11;
    const size_t gbase = ((size_t)((hb * 8 + wv) * 10 + kk)) * 2048;
    *(f16x8*)(s_wlds + (size_t)(kk * 8 + wv) * 2048 + c * 8) =
        *(const f16x8*)(Wn + gbase + c * 8);
  }

  if (w < 2) {
    float s = 0.f;
    for (int j = lane; j < CNN; j += 64) s += img[n * CNN + j] * W_pred[w * 896 + 128 + j];
    for (int off = 32; off; off >>= 1) s += __shfl_down(s, off);
    if (lane == 0) s_pimg[w] = s + b_pred[w];
  }

  float creg[3][4];
  #pragma unroll
  for (int b = 0; b < 3; ++b)
    #pragma unroll
    for (int c = 0; c < 4; ++c) creg[b][c] = 0.f;

  float bias_q[4];
  #pragma unroll
  for (int g = 0; g < 4; ++g) bias_q[g] = bias_n[g * 256 + hb * 128 + w * 16 + cl];

  const f16* gW = Wn + ((size_t)(hb * 8 + w) * 10) * 2048 + (size_t)lane * 8;
  const f16* lW = s_wlds + (size_t)w * 2048 + (size_t)lane * 8;   // + kk*16384 + g*512
  const int e_g = hb * 128 + w * 16 + cl;
  unsigned* myflag = flags + n * 2 + hb;
  unsigned* otflag = flags + n * 2 + (1 - hb);
  int bn = 0;

  __syncthreads();

  // ---- stage t=1 (obs) ----
  {
    for (int i = tid; i < KN * EMB; i += 512) {
      const int k = i >> 6, e = i & 63;
      const float s0 = nstep_g[((n * KN + k) * TOBS + 1) * 2 + 0];
      const float s1 = nstep_g[((n * KN + k) * TOBS + 1) * 2 + 1];
      Ax[k][e] = (f16)(s0 * s_wd0[e] + s1 * s_wd1[e] + s_bd[e]);
    }
    if (tid < 2) {
      s_scal[tid]     = tabs[(n * TOBS + 1) * 2 + tid];
      s_scal[2 + tid] = trel[(n * TOBS + 1) * 2 + tid];
      s_scal[4 + tid] = tstep[(n * TOBS + 1) * 2 + tid];
    }
    if (tid >= 448) {
      const int e = tid - 448;
      const float a0 = tstep[(n * TOBS + 1) * 2 + 0], a1 = tstep[(n * TOBS + 1) * 2 + 1];
      s_x16[e] = (f16)(a0 * s_wd0[e] + a1 * s_wd1[e] + s_bd[e]);
    }
    if (tid >= 384 && tid < 448) {
      const int a = tid - 384;
      const float r0 = trel[(n * TOBS + 1) * 2 + 0], r1 = trel[(n * TOBS + 1) * 2 + 1];
      s_at[a] = r0 * s_wat0[a] + r1 * s_wat1[a] + s_bat[a];
    }
  }
  __syncthreads();

  for (int t = 1; t <= TMAX; ++t) {
    const bool is_obs = (t < TOBS);
    const int tc = is_obs ? t : (TOBS - 1);
    const int gate_t = gt_arr[t];
    const int gate_n = gn_arr[t];
    const float currN = cn_arr[t];
    const bool tmask = is_obs ? (thist > (TOBS - t)) : true;
    const bool do_t = gate_t && tmask;
    const bool need_x = (gate_n || do_t);
    const bool do_att = gate_n && (t >= last29);
    const int par = bn & 1;

    // ---- pred-step top: P0 + x16/at staging (obs steps prestaged last iter) ----
    if (!is_obs) {
      if (w < 2) {
        float s = 0.f;
        for (int j = lane; j < NODE; j += 64) s += s_tht[j] * s_wp[w][j];
        for (int j = lane; j < EDGE; j += 64) s += s_Ht[j] * s_wp[w][128 + j];
        for (int off = 32; off; off >>= 1) s += __shfl_down(s, off);
        if (lane == 0) {
          const float p = s + s_pimg[w];
          const float cabs = s_scal[w] + p;
          const float crel = s_scal[2 + w] + p;
          s_scal[w] = cabs; s_scal[2 + w] = crel; s_scal[4 + w] = p;
          if (hb == 0) out[(n * NPRED + (t - TOBS)) * 2 + w] = crel;
        }
      }
      __syncthreads();  // A
      if (tid >= 448) {
        const int e = tid - 448;
        s_x16[e] = (f16)(s_scal[4] * s_wd0[e] + s_scal[5] * s_wd1[e] + s_bd[e]);
      }
      if (tid >= 384 && tid < 448) {
        const int a = tid - 384;
        s_at[a] = s_scal[2] * s_wat0[a] + s_scal[3] * s_wat1[a] + s_bat[a];
      }
      __syncthreads();  // B
    }

    // ---- P2: nearby LSTM (own 128 e-dims) via MFMA ----
    f16 hreg[3][4];
    if (gate_n) {
      f32x4 acc[3][4];
      #pragma unroll
      for (int rt = 0; rt < 3; ++rt)
        #pragma unroll
        for (int g = 0; g < 4; ++g) acc[rt][g] = (f32x4){0.f, 0.f, 0.f, 0.f};

      #pragma unroll
      for (int kk = 0; kk < 10; ++kk) {
        f16x8 bf[4];
        if (kk < 3) {
          #pragma unroll
          for (int g = 0; g < 4; ++g)
            bf[g] = *(const f16x8*)(lW + kk * 16384 + g * 512);
        } else {
          #pragma unroll
          for (int g = 0; g < 4; ++g)
            bf[g] = *(const f16x8*)(gW + kk * 2048 + g * 512);
        }
        f16x8 af[3];
        #pragma unroll
        for (int rt = 0; rt < 3; ++rt) {
          const int row = rt * 16 + cl;
          const f16* ap = (kk < 2) ? &Ax[row][kk * 32 + koff]
                                   : &Ah[row][(kk - 2) * 32 + koff];
          af[rt] = *(const f16x8*)ap;
        }
        #pragma unroll
        for (int g = 0; g < 4; ++g)
          #pragma unroll
          for (int rt = 0; rt < 3; ++rt)
            acc[rt][g] = __builtin_amdgcn_mfma_f32_16x16x32_f16(af[rt], bf[g], acc[rt][g], 0, 0, 0);
      }

      unsigned* Hg = Hglob + (size_t)(par * NT + n) * (KN * 128);
      #pragma unroll
      for (int rt = 0; rt < 3; ++rt) {
        #pragma unroll
        for (int jj = 0; jj < 4; ++jj) {
          const int row = rt * 16 + kq * 4 + jj;
          const bool nm = is_obs ? (s_nh[row] > (TOBS - t)) : true;
          f16 hv;
          if (nm) {
            const float iv = acc[rt][0][jj] + bias_q[0];
            const float fv = acc[rt][1][jj] + bias_q[1];
            const float gv = acc[rt][2][jj] + bias_q[2];
            const float ov = acc[rt][3][jj] + bias_q[3];
            const float c2 = sigm(fv) * creg[rt][jj] + sigm(iv) * tanh_f(gv);
            creg[rt][jj] = c2;
            hv = (f16)(sigm(ov) * tanh_f(c2));
          } else {
            hv = Ah[row][e_g];
          }
          hreg[rt][jj] = hv;
          const unsigned lo = (unsigned)__builtin_bit_cast(unsigned short, hv);
          const unsigned hi = (unsigned)__shfl_down((int)lo, 1);
          if (!(cl & 1))
            stcoh(Hg + row * 128 + (e_g >> 1), lo | (hi << 16));
        }
      }
    }

    // ---- target gate dots (own 4 gates x 64 node dims) ----
    if (do_t && tid < 256) {
      const int g = tid >> 6, dl = tid & 63;
      const int col = g * 128 + hb * 64 + dl;
      float gg = s_bt[tid];
      const f16x2* xt2 = (const f16x2*)s_x16;
      const f16x2* th2 = (const f16x2*)s_th16;
      const f16x8* wp = (const f16x8*)(Wt + col * 8);
      #pragma unroll
      for (int c8 = 0; c8 < 8; ++c8) {
        const f16x8 wv = wp[c8 * 512];
        #pragma unroll
        for (int j2 = 0; j2 < 4; ++j2) {
          f16x2 wpair = {wv[2 * j2], wv[2 * j2 + 1]};
          gg = __builtin_amdgcn_fdot2(wpair, xt2[c8 * 4 + j2], gg, false);
        }
      }
      #pragma unroll
      for (int c8 = 8; c8 < 24; ++c8) {
        const f16x8 wv = wp[c8 * 512];
        #pragma unroll
        for (int j2 = 0; j2 < 4; ++j2) {
          f16x2 wpair = {wv[2 * j2], wv[2 * j2 + 1]};
          gg = __builtin_amdgcn_fdot2(wpair, th2[(c8 - 8) * 4 + j2], gg, false);
        }
      }
      s_g[tid] = gg;
    }
    // ---- attention scores (only t >= last29) ----
    if (do_att && tid >= 256 && tid < 256 + KN) {
      const int k = tid - 256;
      const float a0 = nabs_g[((n * KN + k) * TOBS + tc) * 2 + 0] - s_scal[0];
      const float a1 = nabs_g[((n * KN + k) * TOBS + tc) * 2 + 1] - s_scal[1];
      const bool nm = is_obs ? (s_nh[k] > (TOBS - t)) : true;
      float sc = 0.f;
      for (int a = 0; a < ATTD; ++a)
        sc += (a0 * s_wan0[a] + a1 * s_wan1[a] + s_ban[a]) * s_at[a];
      sc *= currN * 0.125f;
      s_sc[k] = nm ? sc : 0.f;
      s_w[k]  = nm ? 1.f : 0.f;
    }
    __syncthreads();  // C1

    // ---- cell update + publish; softmax ----
    if (do_t && tid < 64) {
      const int d = hb * 64 + tid;
      const float iv = s_g[tid], fv = s_g[64 + tid];
      const float gv = s_g[128 + tid], ov = s_g[192 + tid];
      const float c2 = sigm(fv) * s_tct[tid] + sigm(iv) * tanh_f(gv);
      s_tct[tid] = c2;
      const float nh = sigm(ov) * tanh_f(c2);
      s_tht[d] = nh;
      s_th16[d] = (f16)nh;
      stcohf(Tglob + ((size_t)(par * NT + n) * 2 + hb) * 64 + tid, nh);
    }
    if (do_att && w == 4) {
      const bool act = lane < KN;
      const float sc = act ? s_sc[lane] : -1.0e30f;
      const float mf = act ? s_w[lane] : 0.f;
      float mx = sc;
      #pragma unroll
      for (int off = 32; off; off >>= 1) mx = fmaxf(mx, __shfl_xor(mx, off));
      float num = __expf(sc - mx) * mf;
      float sum = num;
      #pragma unroll
      for (int off = 32; off; off >>= 1) sum += __shfl_xor(sum, off);
      if (act) s_w[lane] = num * rcp_f(sum + 1e-6f);
    }
    __syncthreads();  // C2: drains all MALL stores (vmcnt(0) before s_barrier)

    if (need_x && tid == 0) {
      stcoh(myflag, (unsigned)(bn + 1));   // publish
    }

    // ---- prestage t+1 (off the serial path, while partner finishes) ----
    {
      const int tn = t + 1;
      if (tn <= TOBS) {
        const int tcn = (tn < TOBS) ? tn : (TOBS - 1);
        for (int i = tid; i < KN * EMB; i += 512) {
          const int k = i >> 6, e = i & 63;
          const float s0 = nstep_g[((n * KN + k) * TOBS + tcn) * 2 + 0];
          const float s1 = nstep_g[((n * KN + k) * TOBS + tcn) * 2 + 1];
          Ax[k][e] = (f16)(s0 * s_wd0[e] + s1 * s_wd1[e] + s_bd[e]);
        }
      }
      if (tn < TOBS) {
        if (tid < 2) {
          s_scal[tid]     = tabs[(n * TOBS + tn) * 2 + tid];
          s_scal[2 + tid] = trel[(n * TOBS + tn) * 2 + tid];
          s_scal[4 + tid] = tstep[(n * TOBS + tn) * 2 + tid];
        }
        if (tid >= 448) {
          const int e = tid - 448;
          const float a0 = tstep[(n * TOBS + tn) * 2 + 0], a1 = tstep[(n * TOBS + tn) * 2 + 1];
          s_x16[e] = (f16)(a0 * s_wd0[e] + a1 * s_wd1[e] + s_bd[e]);
        }
        if (tid >= 384 && tid < 448) {
          const int a = tid - 384;
          const float r0 = trel[(n * TOBS + tn) * 2 + 0], r1 = trel[(n * TOBS + tn) * 2 + 1];
          s_at[a] = r0 * s_wat0[a] + r1 * s_wat1[a] + s_bat[a];
        }
      }
    }

    if (need_x && tid == 0) {
      const unsigned step = (unsigned)(bn + 1);
      while (ldcoh(otflag) < step)
        __builtin_amdgcn_s_sleep(2);
    }
    __syncthreads();  // D

    // ---- pull partner halves ----
    if (gate_n) {
      const unsigned* Hg = Hglob + (size_t)(par * NT + n) * (KN * 128);
      const int ob = (1 - hb) * 64;
      for (int i = tid; i < KN * 64; i += 512) {
        const int row = i >> 6, c = i & 63;
        const unsigned v = ldcoh(Hg + row * 128 + ob + c);
        *(unsigned*)&Ah[row][(ob + c) * 2] = v;
      }
      #pragma unroll
      for (int rt = 0; rt < 3; ++rt)
        #pragma unroll
        for (int jj = 0; jj < 4; ++jj)
          Ah[rt * 16 + kq * 4 + jj][e_g] = hreg[rt][jj];
    }
    if (do_t && tid >= 448) {
      const int dl = tid - 448;
      const int d = (1 - hb) * 64 + dl;
      const float nh = ldcohf(Tglob + ((size_t)(par * NT + n) * 2 + (1 - hb)) * 64 + dl);
      s_tht[d] = nh;
      s_th16[d] = (f16)nh;
    }
    __syncthreads();  // E

    // ---- Ht (only t >= last29) ----
    if (do_att && tid < EDGE) {
      float h = 0.f;
      for (int k = 0; k < KN; ++k) h += (float)Ah[k][tid] * s_w[k];
      s_Ht[tid] = h;
    }
    if (need_x) bn++;
    if (t >= 29) __syncthreads();  // F: only needed before pred P0 reads s_Ht
  }
}

extern "C" void kernel_launch(void* const* d_in, const int* in_sizes, int n_in,
                              void* d_out, int out_size, void* d_ws, size_t ws_size,
                              hipStream_t stream) {
  const float* img    = (const float*)d_in[0];
  const float* tabs   = (const float*)d_in[1];
  const float* trel   = (const float*)d_in[2];
  const float* tstep  = (const float*)d_in[3];
  const float* nabs   = (const float*)d_in[4];
  const float* nstep  = (const float*)d_in[6];
  const int*   thist  = (const int*)d_in[7];
  const int*   nhist  = (const int*)d_in[8];
  const float* W_disp = (const float*)d_in[9];
  const float* b_disp = (const float*)d_in[10];
  const float* Wih_t  = (const float*)d_in[11];
  const float* Whh_t  = (const float*)d_in[12];
  const float* bih_t  = (const float*)d_in[13];
  const float* bhh_t  = (const float*)d_in[14];
  const float* Wih_n  = (const float*)d_in[15];
  const float* Whh_n  = (const float*)d_in[16];
  const float* bih_n  = (const float*)d_in[17];
  const float* bhh_n  = (const float*)d_in[18];
  const float* W_att_t = (const float*)d_in[19];
  const float* b_att_t = (const float*)d_in[20];
  const float* W_att_n = (const float*)d_in[21];
  const float* b_att_n = (const float*)d_in[22];
  const float* W_pred  = (const float*)d_in[23];
  const float* b_pred  = (const float*)d_in[24];

  char* ws = (char*)d_ws;
  f16*      Wn      = (f16*)(ws);              // 655360 B
  f16*      Wt      = (f16*)(ws + 655360);     // 196608 B
  float*    bias_n  = (float*)(ws + 851968);
  float*    bias_t  = (float*)(ws + 856064);
  int*      gt_arr  = (int*)(ws + 858112);
  int*      gn_arr  = (int*)(ws + 858304);
  float*    cn_arr  = (float*)(ws + 858496);
  int*      last29p = (int*)(ws + 859648);
  unsigned* flags   = (unsigned*)(ws + 860160);
  unsigned* Hglob   = (unsigned*)(ws + 1048576);  // 3145728 B
  float*    Tglob   = (float*)(ws + 4194304);     // 131072 B

  prep_kernel<<<64, 512, 0, stream>>>(Wih_n, Whh_n, bih_n, bhh_n, Wih_t, Whh_t,
                                      bih_t, bhh_t, thist, nhist, Wn, Wt,
                                      bias_n, bias_t, gt_arr, gn_arr, cn_arr,
                                      last29p, flags);
  model_kernel<<<2 * NT, 512, 0, stream>>>(img, tabs, trel, tstep, nabs, nstep,
                                           thist, nhist, W_disp, b_disp,
                                           W_att_t, b_att_t, W_att_n, b_att_n,
                                           W_pred, b_pred,
                                           Wn, Wt, bias_n, bias_t,
                                           gt_arr, gn_arr, cn_arr, last29p,
                                           flags, Hglob, Tglob,
                                           (float*)d_out);
}